// Round 8
// baseline (677.849 us; speedup 1.0000x reference)
//
#include <hip/hip_runtime.h>
#include <cstdint>

typedef unsigned short u16;
typedef __attribute__((ext_vector_type(8))) _Float16 f16x8;
typedef __attribute__((ext_vector_type(8))) unsigned short u16x8;
typedef __attribute__((ext_vector_type(4))) float f32x4;

#define SPLITN 7

__device__ __forceinline__ float b2f(u16 u) {
  union { unsigned int i; float f; } v; v.i = ((unsigned int)u) << 16; return v.f;
}
__device__ __forceinline__ u16 f2b(float f) {
  union { float f; unsigned int i; } v; v.f = f;
  unsigned int x = v.i;
  return (u16)((x + 0x7fffu + ((x >> 16) & 1u)) >> 16);
}
__device__ __forceinline__ u16 f2h(float f) {
  union { _Float16 h; u16 u; } v; v.h = (_Float16)f; return v.u;
}
__device__ __forceinline__ float h2f(u16 u) {
  union { u16 u; _Float16 h; } v; v.u = u; return (float)v.h;
}
__device__ __forceinline__ float ld(const void* p, long i, int f) {
  return f ? ((const float*)p)[i] : b2f(((const u16*)p)[i]);
}
template<int F>
__device__ __forceinline__ float4 ld4(const void* p, long i) {
  if (F) return *(const float4*)((const float*)p + i);
  const ushort4 u = *(const ushort4*)((const u16*)p + i);
  return make_float4(b2f(u.x), b2f(u.y), b2f(u.z), b2f(u.w));
}
__device__ __forceinline__ void fma4(float4& a, const float4 x, const float4 k) {
  a.x += x.x * k.x; a.y += x.y * k.y; a.z += x.z * k.z; a.w += x.w * k.w;
}
// tanh-form gelu (max dev from exact erf-gelu ~3e-3, far below threshold)
__device__ __forceinline__ float gelu(float v) {
  const float u = v * (0.7978845608028654f + 0.035677408136300125f * v * v);
  const float e = __expf(2.0f * u);
  return 0.5f * v * (1.0f + (1.0f - 2.0f / (e + 1.0f)));
}
#define GLDS(gp, lp) __builtin_amdgcn_global_load_lds( \
    (const __attribute__((address_space(1))) void*)(gp), \
    (__attribute__((address_space(3))) void*)(lp), 16, 0, 0)

// Kd: dtype sniffer (parallel). flag=1 -> inputs/output are float32.
__global__ __launch_bounds__(256) void detect_kernel(const u16* __restrict__ x,
                                                     int* __restrict__ flag) {
  __shared__ int sbad;
  if (threadIdx.x == 0) sbad = 0;
  __syncthreads();
  int b = 0;
  #pragma unroll
  for (int rr = 0; rr < 2; ++rr) {
    const int i = rr * 256 + threadIdx.x;
    const float v = fabsf(b2f(x[2 * i]));
    if (!(v < 100.f) || v < 1e-6f) ++b;
  }
  atomicAdd(&sbad, b);
  __syncthreads();
  if (threadIdx.x == 0) *flag = (sbad > 16) ? 1 : 0;
}

// K0: all three weight transposes in one dispatch. [R][C] -> fp16 [C][R].
__global__ void transpose_cvt_kernel(const void* __restrict__ w0, u16* __restrict__ o0,
                                     const void* __restrict__ w1, u16* __restrict__ o1,
                                     const void* __restrict__ w2, u16* __restrict__ o2,
                                     const int* __restrict__ flagp) {
  const int f = *flagp;
  int bb = blockIdx.x;
  const void* in; u16* out; int R, C;
  if (bb < 768)       { in = w0; out = o0; R = 256;  C = 768;  }
  else if (bb < 1792) { in = w1; out = o1; R = 256;  C = 1024; bb -= 768; }
  else                { in = w2; out = o2; R = 1024; C = 256;  bb -= 1792; }
  const int o = bb * 256 + threadIdx.x;
  if (o < R * C) {
    const int i = o / R, j = o % R;
    out[o] = f2h(ld(in, (long)j * C + i, f));
  }
}

// ---------------------------------------------------------------------------
// K1: wave per 4-token row group dwconv + group cumsum + LN (unchanged).
template<int F>
__device__ __forceinline__ void dwconv_body4(
    const void* __restrict__ x, const void* __restrict__ dwk, const void* __restrict__ dwb,
    const void* __restrict__ lng, const void* __restrict__ lnb,
    u16* __restrict__ dwc, u16* __restrict__ norm1, int tg, int lane)
{
  const int b = tg / 784, rem = tg % 784;
  const int hh = rem / 14, wg = (rem % 14) * 4;
  const int c0 = lane * 4;
  const long tok0 = (long)b * 3136 + hh * 56 + wg;
  float4 acc[4];
  float4 pv[4];
  if (lane >= 16) {
    const int j0 = c0 - 64;
    const float4 bb = ld4<F>(dwb, j0);
    acc[0] = bb; acc[1] = bb; acc[2] = bb; acc[3] = bb;
    #pragma unroll
    for (int dh = -1; dh <= 1; ++dh) {
      const int h2 = hh + dh;
      if (h2 < 0 || h2 >= 56) continue;
      const long rb = ((long)b * 3136 + h2 * 56) * 256;
      float4 xr[6];
      #pragma unroll
      for (int i = 0; i < 6; ++i) {
        const int w2 = wg - 1 + i;
        xr[i] = (w2 >= 0 && w2 < 56) ? ld4<F>(x, rb + (long)w2 * 256 + c0)
                                     : make_float4(0.f, 0.f, 0.f, 0.f);
      }
      float4 kw[3];
      #pragma unroll
      for (int i = 0; i < 3; ++i)
        kw[i] = ld4<F>(dwk, (long)((dh + 1) * 3 + i) * 192 + j0);
      #pragma unroll
      for (int t = 0; t < 4; ++t)
        #pragma unroll
        for (int i = 0; i < 3; ++i)
          fma4(acc[t], xr[t + i], kw[i]);
    }
  } else {
    #pragma unroll
    for (int t = 0; t < 4; ++t)
      pv[t] = ld4<F>(x, (tok0 + t) * 256 + c0);
  }
  const float4 g = ld4<F>(lng, c0);
  const float4 be = ld4<F>(lnb, c0);
  #pragma unroll
  for (int t = 0; t < 4; ++t) {
    float sx = acc[t].x, sy = acc[t].y, sz = acc[t].z, sw = acc[t].w;
    const float t1x = __shfl(sx, lane - 16), t1y = __shfl(sy, lane - 16),
                t1z = __shfl(sz, lane - 16), t1w = __shfl(sw, lane - 16);
    const float t2x = __shfl(sx, lane - 32), t2y = __shfl(sy, lane - 32),
                t2z = __shfl(sz, lane - 32), t2w = __shfl(sw, lane - 32);
    if (lane >= 32) { sx += t1x; sy += t1y; sz += t1z; sw += t1w; }
    if (lane >= 48) { sx += t2x; sy += t2y; sz += t2z; sw += t2w; }
    float vx, vy, vz, vw;
    if (lane < 16) { vx = pv[t].x; vy = pv[t].y; vz = pv[t].z; vw = pv[t].w; }
    else           { vx = sx;      vy = sy;      vz = sz;      vw = sw;      }
    float sum = vx + vy + vz + vw;
    float sq = vx * vx + vy * vy + vz * vz + vw * vw;
    #pragma unroll
    for (int m = 32; m; m >>= 1) { sum += __shfl_xor(sum, m); sq += __shfl_xor(sq, m); }
    const float mu = sum * (1.0f / 256.0f);
    const float var = sq * (1.0f / 256.0f) - mu * mu;
    const float rstd = rsqrtf(fmaxf(var, 0.f) + 1e-6f);
    ushort4 dv, nv;
    dv.x = f2h(vx); dv.y = f2h(vy); dv.z = f2h(vz); dv.w = f2h(vw);
    nv.x = f2h((vx - mu) * rstd * g.x + be.x);
    nv.y = f2h((vy - mu) * rstd * g.y + be.y);
    nv.z = f2h((vz - mu) * rstd * g.z + be.z);
    nv.w = f2h((vw - mu) * rstd * g.w + be.w);
    *(ushort4*)(dwc + (tok0 + t) * 256 + c0) = dv;
    *(ushort4*)(norm1 + (tok0 + t) * 256 + c0) = nv;
  }
}

__global__ __launch_bounds__(256) void dwconv_ln_kernel(
    const void* __restrict__ x, const void* __restrict__ dwk, const void* __restrict__ dwb,
    const void* __restrict__ lng, const void* __restrict__ lnb,
    u16* __restrict__ dwc, u16* __restrict__ norm1, const int* __restrict__ flagp)
{
  const int wave = threadIdx.x >> 6, lane = threadIdx.x & 63;
  const int tg = blockIdx.x * 4 + wave;
  if (*flagp) dwconv_body4<1>(x, dwk, dwb, lng, lnb, dwc, norm1, tg, lane);
  else        dwconv_body4<0>(x, dwk, dwb, lng, lnb, dwc, norm1, tg, lane);
}

// ---------------------------------------------------------------------------
// sgemm: A-tile (64x256) staged ONCE into LDS (XOR granule swizzle, 1 barrier),
// B streamed as register fragments straight from global (B^T rows, 16B each).
// 2x2 wave grid: WM=32 (MI=2), WN=64 (NI=4), K=256 (8 MFMA k-steps), no K-loop
// barriers at all. EPI 5: qkv split write; EPI 2: +bias+aux(fp16)+BN.
template<int EPI>
__global__ __launch_bounds__(256, 4) void sgemm_kernel(
    const u16* __restrict__ A, const u16* __restrict__ Bt, void* C,
    int ldb, long aZ, long bZ, long cZ, long zoff,
    const void* __restrict__ bias, const void* aux,
    const void* __restrict__ bng, const void* __restrict__ bnb,
    const void* __restrict__ bnm, const void* __restrict__ bnv,
    const int* __restrict__ flagp)
{
  __shared__ __align__(16) u16 Ds[64 * 256];
  const int f = (EPI == 5) ? 0 : *flagp;
  const int tid = threadIdx.x;
  const int wave = tid >> 6, lane = tid & 63;
  const int quad = lane >> 4, l16 = lane & 15;
  const int wr = wave >> 1, wc = wave & 1;
  const int tileM = blockIdx.y * 64, colC = blockIdx.x * 128;
  const u16* Ab = A + (long)blockIdx.z * aZ + (long)tileM * 256;
  const u16* Bb = Bt + (long)blockIdx.z * bZ;

  #pragma unroll
  for (int r = 0; r < 8; ++r) {
    const int fg = r * 256 + tid;
    const int row = fg >> 5, cs = (fg & 31) ^ (row & 7);
    GLDS(Ab + (long)row * 256 + cs * 8, Ds + (r * 256 + wave * 64) * 8);
  }
  __syncthreads();

  f32x4 acc[2][4];
  #pragma unroll
  for (int mi = 0; mi < 2; ++mi)
    #pragma unroll
    for (int ni = 0; ni < 4; ++ni)
      acc[mi][ni] = (f32x4){0.f, 0.f, 0.f, 0.f};

  #pragma unroll
  for (int kk = 0; kk < 8; ++kk) {
    const int kc = kk * 4 + quad;
    f16x8 af[2], bf[4];
    #pragma unroll
    for (int mi = 0; mi < 2; ++mi) {
      const int R = wr * 32 + mi * 16 + l16;
      af[mi] = *(const f16x8*)&Ds[(R * 32 + (kc ^ (R & 7))) * 8];
    }
    #pragma unroll
    for (int ni = 0; ni < 4; ++ni) {
      const int S = colC + wc * 64 + ni * 16 + l16;
      bf[ni] = *(const f16x8*)(Bb + (long)S * ldb + kc * 8);
    }
    #pragma unroll
    for (int mi = 0; mi < 2; ++mi)
      #pragma unroll
      for (int ni = 0; ni < 4; ++ni)
        acc[mi][ni] = __builtin_amdgcn_mfma_f32_16x16x32_f16(af[mi], bf[ni], acc[mi][ni], 0, 0, 0);
  }

  #pragma unroll
  for (int mi = 0; mi < 2; ++mi)
    #pragma unroll
    for (int ni = 0; ni < 4; ++ni) {
      const int col = colC + wc * 64 + ni * 16 + l16;
      #pragma unroll
      for (int r = 0; r < 4; ++r) {
        const int rloc = wr * 32 + mi * 16 + quad * 4 + r;
        float v = acc[mi][ni][r];
        if (EPI == 2) {
          const long ci = (long)blockIdx.z * cZ + (long)(tileM + rloc) * 256 + col;
          v += ld(bias, col, f);
          v += h2f(((const u16*)aux)[ci]);
          v = (v - ld(bnm, col, f)) * rsqrtf(ld(bnv, col, f) + 1e-3f) * ld(bng, col, f) + ld(bnb, col, f);
          ((u16*)C)[ci] = f2h(v);
        } else {  // EPI 5: qk (cols 0..511, ldc 512) / v (cols 512.., ldc 256)
          const long row = tileM + rloc;
          if (col < 512) ((u16*)C)[row * 512 + col] = f2h(v);
          else ((u16*)aux)[zoff + row * 256 + (col - 512)] = f2h(v);
        }
      }
    }
}

// ---------------------------------------------------------------------------
// K-MLP v2: fc1+gelu+fc2+residual. A-tile LDS once; W1/W2 as register
// fragments from global (no B staging, no K-loop barriers). Hs padded to 136
// halfs/row (16B-aligned rows, <=2-way banks). 2 barriers per h-chunk.
__global__ __launch_bounds__(256, 3) void mlp_kernel(
    const u16* __restrict__ dwc, const u16* __restrict__ w1t, const u16* __restrict__ w2t,
    const void* __restrict__ b1, const void* __restrict__ b2,
    const void* __restrict__ x, void* __restrict__ out,
    const int* __restrict__ flagp)
{
  __shared__ __align__(16) u16 Ds[64 * 256];   // 32 KB
  __shared__ __align__(16) u16 Hs[64 * 136];   // 17 KB (136-half rows)
  const int f = *flagp;
  const int tid = threadIdx.x;
  const int wave = tid >> 6, lane = tid & 63;
  const int quad = lane >> 4, l16 = lane & 15;
  const int wr = wave >> 1, wc = wave & 1;
  const int tileM = blockIdx.x * 64;

  #pragma unroll
  for (int r = 0; r < 8; ++r) {
    const int fg = r * 256 + tid;
    const int row = fg >> 5, cs = (fg & 31) ^ (row & 7);
    GLDS(dwc + (long)(tileM + row) * 256 + cs * 8, Ds + (r * 256 + wave * 64) * 8);
  }
  __syncthreads();

  f32x4 accO[2][8];
  #pragma unroll
  for (int mi = 0; mi < 2; ++mi)
    #pragma unroll
    for (int ni = 0; ni < 8; ++ni)
      accO[mi][ni] = (f32x4){0.f, 0.f, 0.f, 0.f};

  for (int hc = 0; hc < 8; ++hc) {
    // ---- fc1: h[64x128-chunk] = Ds @ W1-cols, B from global registers ----
    f32x4 acc1[2][4];
    #pragma unroll
    for (int mi = 0; mi < 2; ++mi)
      #pragma unroll
      for (int ni = 0; ni < 4; ++ni)
        acc1[mi][ni] = (f32x4){0.f, 0.f, 0.f, 0.f};
    #pragma unroll
    for (int kk = 0; kk < 8; ++kk) {
      const int kc = kk * 4 + quad;
      f16x8 af[2], bf[4];
      #pragma unroll
      for (int mi = 0; mi < 2; ++mi) {
        const int R = wr * 32 + mi * 16 + l16;
        af[mi] = *(const f16x8*)&Ds[(R * 32 + (kc ^ (R & 7))) * 8];
      }
      #pragma unroll
      for (int ni = 0; ni < 4; ++ni) {
        const int S = hc * 128 + wc * 64 + ni * 16 + l16;
        bf[ni] = *(const f16x8*)(w1t + (long)S * 256 + kc * 8);
      }
      #pragma unroll
      for (int mi = 0; mi < 2; ++mi)
        #pragma unroll
        for (int ni = 0; ni < 4; ++ni)
          acc1[mi][ni] = __builtin_amdgcn_mfma_f32_16x16x32_f16(af[mi], bf[ni], acc1[mi][ni], 0, 0, 0);
    }
    // ---- gelu -> Hs ----
    #pragma unroll
    for (int mi = 0; mi < 2; ++mi)
      #pragma unroll
      for (int ni = 0; ni < 4; ++ni)
        #pragma unroll
        for (int r = 0; r < 4; ++r) {
          const int row = wr * 32 + mi * 16 + quad * 4 + r;
          const int col = wc * 64 + ni * 16 + l16;
          const float v = acc1[mi][ni][r] + ld(b1, hc * 128 + col, f);
          Hs[row * 136 + col] = f2h(gelu(v));
        }
    __syncthreads();
    // ---- fc2 partial: accO += Hs @ W2-rows-chunk, B from global registers ----
    #pragma unroll
    for (int kk2 = 0; kk2 < 4; ++kk2) {
      const int kc2 = kk2 * 4 + quad;
      f16x8 af[2], bf[8];
      #pragma unroll
      for (int mi = 0; mi < 2; ++mi) {
        const int R = wr * 32 + mi * 16 + l16;
        af[mi] = *(const f16x8*)&Hs[R * 136 + kc2 * 8];
      }
      #pragma unroll
      for (int ni = 0; ni < 8; ++ni) {
        const int S = wc * 128 + ni * 16 + l16;
        bf[ni] = *(const f16x8*)(w2t + (long)S * 1024 + hc * 128 + kc2 * 8);
      }
      #pragma unroll
      for (int mi = 0; mi < 2; ++mi)
        #pragma unroll
        for (int ni = 0; ni < 8; ++ni)
          accO[mi][ni] = __builtin_amdgcn_mfma_f32_16x16x32_f16(af[mi], bf[ni], accO[mi][ni], 0, 0, 0);
    }
    __syncthreads();  // Hs safe to overwrite next hc
  }
  // ---- epilogue: out = accO + b2 + x ----
  #pragma unroll
  for (int mi = 0; mi < 2; ++mi)
    #pragma unroll
    for (int ni = 0; ni < 8; ++ni) {
      const int col = wc * 128 + ni * 16 + l16;
      #pragma unroll
      for (int r = 0; r < 4; ++r) {
        const int row = tileM + wr * 32 + mi * 16 + quad * 4 + r;
        const long ci = (long)row * 256 + col;
        const float v = accO[mi][ni][r] + ld(b2, col, f) + ld(x, ci, f);
        if (f) ((float*)out)[ci] = v; else ((u16*)out)[ci] = f2b(v);
      }
    }
}

// ---------------------------------------------------------------------------
// K3: MFMA attention accumulation (unchanged).
__global__ __launch_bounds__(256) void attn_accum_kernel(
    const u16* __restrict__ qk, float* __restrict__ A_part, int pair0)
{
  const int pl = blockIdx.x;
  const int split = blockIdx.y;
  const int bl = pl >> 3, h = pl & 7;
  const int tid = threadIdx.x;
  const int wave = tid >> 6, lane = tid & 63;
  const int quad = lane >> 4, l16 = lane & 15;
  const int dq = wave >> 1, eq = wave & 1;
  __shared__ __align__(16) u16 lqT[32 * 72];
  __shared__ __align__(16) u16 lkT[32 * 72];
  const long rowbase = (long)bl * 3136 * 512;
  const int n0 = split * 448;
  f32x4 acc = (f32x4){0.f, 0.f, 0.f, 0.f};
  const int seg = tid & 7;

  for (int ch = 0; ch < 7; ++ch) {
    const int nb = n0 + ch * 64;
    #pragma unroll
    for (int rr = 0; rr < 2; ++rr) {
      const int a = rr * 256 + tid;
      const int nl = a >> 3;
      const int co = (seg < 4) ? h * 32 + seg * 8 : 256 + h * 32 + (seg - 4) * 8;
      const u16x8 v8 = *(const u16x8*)(qk + rowbase + (long)(nb + nl) * 512 + co);
      float vf[8], p = 0.f;
      #pragma unroll
      for (int i = 0; i < 8; ++i) { vf[i] = h2f(v8[i]); p += vf[i] * vf[i]; }
      float p1 = p + __shfl_xor(p, 1);
      float p2 = p1 + __shfl_xor(p1, 2);
      const float other = __shfl_xor(p2, 4);
      const float ssq = (seg < 4) ? p2 : other;
      const float ssk = (seg < 4) ? other : p2;
      const float s = 0.17677669529663687f * rsqrtf(fmaxf(ssq, 1e-12f)) *
                      rsqrtf(fmaxf(ssk, 1e-12f));
      if (seg < 4) {
        const int db = seg * 8;
        #pragma unroll
        for (int i = 0; i < 8; ++i) {
          const int d = db + i;
          lqT[d * 72 + (nl ^ (d & 24))] = f2h(vf[i] * s);
        }
      } else {
        const int eb = (seg - 4) * 8;
        #pragma unroll
        for (int i = 0; i < 8; ++i) {
          const int e = eb + i;
          lkT[e * 72 + (nl ^ (e & 24))] = v8[i];
        }
      }
    }
    __syncthreads();
    #pragma unroll
    for (int ks = 0; ks < 2; ++ks) {
      const int tb = ks * 32 + quad * 8;
      const int dA = dq * 16 + l16;
      const int eB = eq * 16 + l16;
      const f16x8 af = *(const f16x8*)&lqT[dA * 72 + (tb ^ (dA & 24))];
      const f16x8 bf = *(const f16x8*)&lkT[eB * 72 + (tb ^ (eB & 24))];
      acc = __builtin_amdgcn_mfma_f32_16x16x32_f16(af, bf, acc, 0, 0, 0);
    }
    __syncthreads();
  }
  float* o = A_part + ((long)(pair0 + pl) * SPLITN + split) * 1024;
  #pragma unroll
  for (int r = 0; r < 4; ++r)
    o[(dq * 16 + quad * 4 + r) * 32 + eq * 16 + l16] = acc[r];
}

__global__ __launch_bounds__(1024) void softmax_kernel(float* A_part) {
  const int pair = blockIdx.x;
  const int t = threadIdx.x;
  float v = 0.f;
  float* base = A_part + (long)pair * SPLITN * 1024 + t;
  #pragma unroll
  for (int s = 0; s < SPLITN; ++s) v += base[s * 1024];
  float mx = v;
  #pragma unroll
  for (int m = 16; m; m >>= 1) mx = fmaxf(mx, __shfl_xor(mx, m, 32));
  const float p = expf(v - mx);
  float sm = p;
  #pragma unroll
  for (int m = 16; m; m >>= 1) sm += __shfl_xor(sm, m, 32);
  base[0] = p / sm;
}

__global__ __launch_bounds__(256) void wb_kernel(
    const float* __restrict__ A_part, const void* __restrict__ proj_w,
    u16* __restrict__ Wbt, const int* __restrict__ flagp)
{
  const int f = *flagp;
  const int b = blockIdx.x;
  const int cs = blockIdx.y;
  const int tid = threadIdx.x;
  const int cg = tid & 31, dg = tid >> 5;
  const int c = cs * 32 + cg;
  __shared__ float Ah[32][32];
  __shared__ float pw[32][33];
  for (int h = 0; h < 8; ++h) {
    const float* Abase = A_part + ((long)(b * 8 + h) * SPLITN) * 1024;
    #pragma unroll
    for (int rr = 0; rr < 4; ++rr) {
      const int ff = rr * 256 + tid;
      Ah[ff >> 5][ff & 31] = Abase[ff];
    }
    #pragma unroll
    for (int rr = 0; rr < 4; ++rr) {
      const int ff = rr * 256 + tid;
      const int e = ff >> 5, ccc = ff & 31;
      pw[e][ccc] = ld(proj_w, (long)(h * 32 + e) * 256 + cs * 32 + ccc, f);
    }
    __syncthreads();
    float acc[4] = {0.f, 0.f, 0.f, 0.f};
    #pragma unroll
    for (int e = 0; e < 32; ++e) {
      const float pv = pw[e][cg];
      #pragma unroll
      for (int dd = 0; dd < 4; ++dd)
        acc[dd] += Ah[dg * 4 + dd][e] * pv;
    }
    #pragma unroll
    for (int dd = 0; dd < 4; ++dd)
      Wbt[((long)b * 256 + c) * 256 + h * 32 + dg * 4 + dd] = f2h(acc[dd]);
    __syncthreads();
  }
}

extern "C" void kernel_launch(void* const* d_in, const int* in_sizes, int n_in,
                              void* d_out, int out_size, void* d_ws, size_t ws_size,
                              hipStream_t stream) {
  const void* x      = d_in[0];
  const void* dwk    = d_in[1];
  const void* dwb    = d_in[2];
  const void* lng    = d_in[3];
  const void* lnb    = d_in[4];
  const void* qkv_w  = d_in[5];
  const void* proj_w = d_in[6];
  const void* proj_b = d_in[7];
  const void* bn_g   = d_in[8];
  const void* bn_b   = d_in[9];
  const void* bn_m   = d_in[10];
  const void* bn_v   = d_in[11];
  const void* fc1_w  = d_in[12];
  const void* fc1_b  = d_in[13];
  const void* fc2_w  = d_in[14];
  const void* fc2_b  = d_in[15];
  char* ws = (char*)d_ws;

  int*   flagp   = (int*)  (ws + 0);
  u16*   wqkvT   = (u16*)  (ws + 256);
  u16*   wfc1T   = (u16*)  (ws + 393472);
  u16*   wfc2T   = (u16*)  (ws + 917760);
  float* A_part  = (float*)(ws + 1442048);
  u16*   Wbt     = (u16*)  (ws + 5112064);
  u16*   vbuf    = (u16*)  (ws + 7209216);
  u16*   dwc     = (u16*)  (ws + 32899328);
  u16*   qk_half = (u16*)  (ws + 58589440);
  u16*   norm1   = (u16*)d_out;  // fp16-bit scratch; dead before mlp writes out

  detect_kernel<<<1, 256, 0, stream>>>((const u16*)x, flagp);

  transpose_cvt_kernel<<<2816, 256, 0, stream>>>(qkv_w, wqkvT, fc1_w, wfc1T,
                                                 fc2_w, wfc2T, flagp);

  dwconv_ln_kernel<<<3136, 256, 0, stream>>>(x, dwk, dwb, lng, lnb, dwc, norm1, flagp);

  for (int half = 0; half < 2; ++half) {
    const u16* nh = norm1 + (long)half * 25088 * 256;
    sgemm_kernel<5><<<dim3(6, 392, 1), 256, 0, stream>>>(
        nh, wqkvT, qk_half, 256, 0, 0, 0, (long)half * 25088 * 256,
        nullptr, vbuf, nullptr, nullptr, nullptr, nullptr, flagp);
    attn_accum_kernel<<<dim3(64, SPLITN), 256, 0, stream>>>(qk_half, A_part, half * 64);
  }

  softmax_kernel<<<128, 1024, 0, stream>>>(A_part);
  wb_kernel<<<dim3(16, 8), 256, 0, stream>>>(A_part, proj_w, Wbt, flagp);

  // merged = BN( V @ W_b + proj_b + dwconv ) — in-place into dwc
  sgemm_kernel<2><<<dim3(2, 49, 16), 256, 0, stream>>>(
      vbuf, Wbt, dwc, 256, (long)3136 * 256, 65536, (long)3136 * 256, 0,
      proj_b, dwc, bn_g, bn_b, bn_m, bn_v, flagp);

  // fused MLP: out = x + gelu(merged @ W1 + b1) @ W2 + b2
  mlp_kernel<<<784, 256, 0, stream>>>(dwc, wfc1T, wfc2T, fc1_b, fc2_b, x, d_out, flagp);
}